// Round 5
// baseline (4257.909 us; speedup 1.0000x reference)
//
#include <hip/hip_runtime.h>
#include <hip/hip_bf16.h>
#include <cstddef>

#define B_ 8
#define H_ 256
#define W_ 256

static constexpr int NPIX = B_ * H_ * W_;   // 524288

__device__ __forceinline__ float4 ld4(const float* p) { return *(const float4*)p; }

// ---------------------------------------------------------------------------
// dense_image_warp (TFA semantics): out[b,i,j,c] = bilinear(img[b],
//   (i - flow[...,0], j - flow[...,1])), floors clamped to [0,size-2],
//   alphas clamped to [0,1]. 8 threads per pixel, float4 channels.
// ---------------------------------------------------------------------------
__global__ __launch_bounds__(256) void warp_kernel(
    const float* __restrict__ img, const float* __restrict__ flow,
    float* __restrict__ out)
{
    int gid = blockIdx.x * 256 + threadIdx.x;
    int p   = gid >> 3;
    int c4  = (gid & 7) << 2;
    int b   = p >> 16;
    int i   = (p >> 8) & 255;
    int j   = p & 255;
    float2 f = *(const float2*)(flow + (size_t)p * 2);
    float qy = (float)i - f.x;
    float qx = (float)j - f.y;
    float fyf = fminf(fmaxf(floorf(qy), 0.0f), (float)(H_ - 2));
    float fxf = fminf(fmaxf(floorf(qx), 0.0f), (float)(W_ - 2));
    float ay = fminf(fmaxf(qy - fyf, 0.0f), 1.0f);
    float ax = fminf(fmaxf(qx - fxf, 0.0f), 1.0f);
    int fy = (int)fyf, fx = (int)fxf;
    const float* base = img + ((((size_t)b * H_ + fy) * W_ + fx) << 5) + c4;
    float4 tl = ld4(base);
    float4 tr = ld4(base + 32);
    float4 bl = ld4(base + W_ * 32);
    float4 br = ld4(base + W_ * 32 + 32);
    float4 r;
    { float t = tl.x + ax * (tr.x - tl.x); float u = bl.x + ax * (br.x - bl.x); r.x = t + ay * (u - t); }
    { float t = tl.y + ax * (tr.y - tl.y); float u = bl.y + ax * (br.y - bl.y); r.y = t + ay * (u - t); }
    { float t = tl.z + ax * (tr.z - tl.z); float u = bl.z + ax * (br.z - bl.z); r.z = t + ay * (u - t); }
    { float t = tl.w + ax * (tr.w - tl.w); float u = bl.w + ax * (br.w - bl.w); r.w = t + ay * (u - t); }
    *(float4*)(out + ((size_t)p << 5) + c4) = r;
}

// ---------------------------------------------------------------------------
// conv0: 3x3, Cin=64 (= concat[srcA(ch 0..31), srcB(ch 32..63)]), Cout=32,
// ReLU. Simple form: 1 pixel/thread, weights in LDS (wave-uniform broadcast
// reads). SAME zero-padding via tap skip.
// ---------------------------------------------------------------------------
__global__ __launch_bounds__(256) void conv0_kernel(
    const float* __restrict__ srcA, const float* __restrict__ srcB,
    const float* __restrict__ w, const float* __restrict__ bias,
    float* __restrict__ out)
{
    __shared__ float sw[9 * 64 * 32];
    __shared__ float sb[32];
    int tid = threadIdx.x;
    for (int i = tid; i < 9 * 64 * 32; i += 256) sw[i] = w[i];
    if (tid < 32) sb[tid] = bias[tid];
    __syncthreads();

    int p = blockIdx.x * 256 + tid;
    int y = (p >> 8) & 255, x = p & 255;

    float acc[32];
#pragma unroll
    for (int c = 0; c < 32; ++c) acc[c] = sb[c];

    for (int dy = -1; dy <= 1; ++dy)
    for (int dx = -1; dx <= 1; ++dx) {
        if ((unsigned)(y + dy) >= (unsigned)H_) continue;
        if ((unsigned)(x + dx) >= (unsigned)W_) continue;
        int q = p + dy * W_ + dx;
        const float* a = srcA + ((size_t)q << 5);
        const float* b = srcB + ((size_t)q << 5);
        const float* wt = &sw[((dy + 1) * 3 + (dx + 1)) * 64 * 32];
#pragma unroll 1
        for (int ci = 0; ci < 32; ++ci) {
            float va = a[ci];
            float vb = b[ci];
            const float* wa = wt + ci * 32;
            const float* wb = wt + (32 + ci) * 32;
#pragma unroll
            for (int c = 0; c < 32; ++c) acc[c] += va * wa[c];
#pragma unroll
            for (int c = 0; c < 32; ++c) acc[c] += vb * wb[c];
        }
    }

    float* o = out + ((size_t)p << 5);
#pragma unroll
    for (int c4 = 0; c4 < 8; ++c4) {
        float4 r;
        r.x = fmaxf(acc[c4 * 4 + 0], 0.f);
        r.y = fmaxf(acc[c4 * 4 + 1], 0.f);
        r.z = fmaxf(acc[c4 * 4 + 2], 0.f);
        r.w = fmaxf(acc[c4 * 4 + 3], 0.f);
        *(float4*)(o + c4 * 4) = r;
    }
}

// ---------------------------------------------------------------------------
// conv1 (3x3, 32->64, ReLU) + 1x1 chain 64->64(relu)->16(relu)->2(linear)
// + flow add. Simple form: 1 pixel/thread; h1/t2/t3 register arrays fully
// statically indexed (unrolled loops).
// ---------------------------------------------------------------------------
__global__ __launch_bounds__(256) void conv1_chain_kernel(
    const float* __restrict__ h0,
    const float* __restrict__ w1, const float* __restrict__ b1,
    const float* __restrict__ w2, const float* __restrict__ b2,
    const float* __restrict__ w3, const float* __restrict__ b3,
    const float* __restrict__ w4, const float* __restrict__ b4,
    const float* __restrict__ flow, float* __restrict__ fc)
{
    __shared__ float sw1[9 * 32 * 64];
    __shared__ float sw2[64 * 64];
    __shared__ float sw3[64 * 16];
    __shared__ float sw4[16 * 2];
    __shared__ float sb1[64], sb2[64], sb3[16], sb4[2];
    int tid = threadIdx.x;
    for (int i = tid; i < 9 * 32 * 64; i += 256) sw1[i] = w1[i];
    for (int i = tid; i < 64 * 64; i += 256) sw2[i] = w2[i];
    for (int i = tid; i < 64 * 16; i += 256) sw3[i] = w3[i];
    if (tid < 32) sw4[tid] = w4[tid];
    if (tid < 64) sb1[tid] = b1[tid];
    else if (tid < 128) sb2[tid - 64] = b2[tid - 64];
    else if (tid < 144) sb3[tid - 128] = b3[tid - 128];
    else if (tid < 146) sb4[tid - 144] = b4[tid - 144];
    __syncthreads();

    int p = blockIdx.x * 256 + tid;
    int y = (p >> 8) & 255, x = p & 255;

    float h1[64];
#pragma unroll
    for (int c = 0; c < 64; ++c) h1[c] = sb1[c];

    for (int dy = -1; dy <= 1; ++dy)
    for (int dx = -1; dx <= 1; ++dx) {
        if ((unsigned)(y + dy) >= (unsigned)H_) continue;
        if ((unsigned)(x + dx) >= (unsigned)W_) continue;
        int q = p + dy * W_ + dx;
        const float* n = h0 + ((size_t)q << 5);
        const float* wt = &sw1[((dy + 1) * 3 + (dx + 1)) * 32 * 64];
#pragma unroll 1
        for (int ci = 0; ci < 32; ++ci) {
            float v = n[ci];
            const float* wr = wt + ci * 64;
#pragma unroll
            for (int c = 0; c < 64; ++c) h1[c] += v * wr[c];
        }
    }
#pragma unroll
    for (int c = 0; c < 64; ++c) h1[c] = fmaxf(h1[c], 0.f);

    // 1x1: 64 -> 64, relu applied on use
    float t2[64];
#pragma unroll
    for (int c = 0; c < 64; ++c) t2[c] = sb2[c];
#pragma unroll
    for (int ci = 0; ci < 64; ++ci) {
        float v = h1[ci];
        const float* wr = &sw2[ci * 64];
#pragma unroll
        for (int c = 0; c < 64; ++c) t2[c] += v * wr[c];
    }

    // 1x1: 64 -> 16
    float t3[16];
#pragma unroll
    for (int c = 0; c < 16; ++c) t3[c] = sb3[c];
#pragma unroll
    for (int ci = 0; ci < 64; ++ci) {
        float v = fmaxf(t2[ci], 0.f);
        const float* wr = &sw3[ci * 16];
#pragma unroll
        for (int c = 0; c < 16; ++c) t3[c] += v * wr[c];
    }

    // 1x1: 16 -> 2 (linear) + flow add
    float o0 = sb4[0], o1 = sb4[1];
#pragma unroll
    for (int ci = 0; ci < 16; ++ci) {
        float v = fmaxf(t3[ci], 0.f);
        o0 += v * sw4[ci * 2 + 0];
        o1 += v * sw4[ci * 2 + 1];
    }
    float2 fl = *(const float2*)(flow + (size_t)p * 2);
    float2 r; r.x = fl.x + o0; r.y = fl.y + o1;
    *(float2*)(fc + (size_t)p * 2) = r;
}

// ---------------------------------------------------------------------------
// 2x bilinear upsample, jax.image.resize half-pixel convention:
// in_coord = (out+0.5)*0.5 - 0.5; edge renormalization == clamping for the
// triangle kernel at scale 2.
// ---------------------------------------------------------------------------
__global__ __launch_bounds__(256) void upsample_kernel(
    const float* __restrict__ fc, float* __restrict__ out)
{
    int gid = blockIdx.x * 256 + threadIdx.x;   // B*512*512 threads
    int b  = gid >> 18;
    int oy = (gid >> 9) & 511;
    int ox = gid & 511;
    float iy = 0.5f * (float)oy - 0.25f;
    float ix = 0.5f * (float)ox - 0.25f;
    float y0f = floorf(iy), x0f = floorf(ix);
    float wy = iy - y0f, wx = ix - x0f;
    int y0 = min(max((int)y0f, 0), H_ - 1);
    int y1 = min(max((int)y0f + 1, 0), H_ - 1);
    int x0 = min(max((int)x0f, 0), W_ - 1);
    int x1 = min(max((int)x0f + 1, 0), W_ - 1);
    float2 v00 = *(const float2*)(fc + (((size_t)b * H_ + y0) * W_ + x0) * 2);
    float2 v01 = *(const float2*)(fc + (((size_t)b * H_ + y0) * W_ + x1) * 2);
    float2 v10 = *(const float2*)(fc + (((size_t)b * H_ + y1) * W_ + x0) * 2);
    float2 v11 = *(const float2*)(fc + (((size_t)b * H_ + y1) * W_ + x1) * 2);
    float2 r;
    { float t = v00.x + wx * (v01.x - v00.x); float u = v10.x + wx * (v11.x - v10.x); r.x = t + wy * (u - t); }
    { float t = v00.y + wx * (v01.y - v00.y); float u = v10.y + wx * (v11.y - v10.y); r.y = t + wy * (u - t); }
    *(float2*)(out + (size_t)gid * 2) = r;
}

// ---------------------------------------------------------------------------
// Input order is setup_inputs() DICT order, which interleaves directions
// per layer:  4+4i+0 = w12_i, 4+4i+1 = b12_i, 4+4i+2 = w21_i, 4+4i+3 = b21_i.
// (NOT the reference signature order — that cost rounds 3 & 4.)
// ---------------------------------------------------------------------------
extern "C" void kernel_launch(void* const* d_in, const int* in_sizes, int n_in,
                              void* d_out, int out_size, void* d_ws, size_t ws_size,
                              hipStream_t stream)
{
    (void)in_sizes; (void)n_in; (void)out_size; (void)ws_size;
    const float* input1 = (const float*)d_in[0];
    const float* input2 = (const float*)d_in[1];
    float* ws = (float*)d_ws;
    float* warped1 = ws;                               // NPIX*32
    float* h0      = ws + (size_t)NPIX * 32;           // NPIX*32
    float* fcbuf   = ws + (size_t)NPIX * 64;           // NPIX*2
    float* outf    = (float*)d_out;

    for (int d = 0; d < 2; ++d) {
        const float* src   = (d == 0) ? input1 : input2;
        const float* other = (d == 0) ? input2 : input1;
        const float* flow  = (const float*)d_in[2 + d];
        const float* w0 = (const float*)d_in[4 + 4 * 0 + 2 * d];
        const float* b0 = (const float*)d_in[5 + 4 * 0 + 2 * d];
        const float* w1 = (const float*)d_in[4 + 4 * 1 + 2 * d];
        const float* b1 = (const float*)d_in[5 + 4 * 1 + 2 * d];
        const float* w2 = (const float*)d_in[4 + 4 * 2 + 2 * d];
        const float* b2 = (const float*)d_in[5 + 4 * 2 + 2 * d];
        const float* w3 = (const float*)d_in[4 + 4 * 3 + 2 * d];
        const float* b3 = (const float*)d_in[5 + 4 * 3 + 2 * d];
        const float* w4 = (const float*)d_in[4 + 4 * 4 + 2 * d];
        const float* b4 = (const float*)d_in[5 + 4 * 4 + 2 * d];
        float* out_warp = outf + (size_t)d * NPIX * 32;
        float* out_up   = outf + (size_t)2 * NPIX * 32 + (size_t)d * (B_ * 512 * 512 * 2);

        warp_kernel<<<NPIX * 8 / 256, 256, 0, stream>>>(src, flow, warped1);
        conv0_kernel<<<NPIX / 256, 256, 0, stream>>>(other, warped1, w0, b0, h0);
        conv1_chain_kernel<<<NPIX / 256, 256, 0, stream>>>(h0, w1, b1, w2, b2, w3, b3, w4, b4, flow, fcbuf);
        warp_kernel<<<NPIX * 8 / 256, 256, 0, stream>>>(src, fcbuf, out_warp);
        upsample_kernel<<<B_ * 512 * 512 / 256, 256, 0, stream>>>(fcbuf, out_up);
    }
}

// Round 8
// 616.060 us; speedup vs baseline: 6.9115x; 6.9115x over previous
//
#include <hip/hip_runtime.h>
#include <hip/hip_bf16.h>
#include <cstddef>

#define B_ 8
#define H_ 256
#define W_ 256

static constexpr int NPIX = B_ * H_ * W_;   // 524288

typedef __attribute__((ext_vector_type(8))) short bf16x8;   // 8 bf16 (4 VGPRs)
typedef __attribute__((ext_vector_type(4))) float f32x4;

__device__ __forceinline__ float4 ld4(const float* p) { return *(const float4*)p; }

// RNE f32 -> bf16 bits (finite data only)
__device__ __forceinline__ short f2bf(float x) {
    unsigned u = __float_as_uint(x);
    unsigned r = (u + 0x7fffu + ((u >> 16) & 1u)) >> 16;
    return (short)r;
}

// ---------------------------------------------------------------------------
// Convert f32 NHWC inputs -> bf16 copies (xb1, xb2). 8 floats/thread.
// ---------------------------------------------------------------------------
__global__ __launch_bounds__(256) void cvt_inputs_kernel(
    const float* __restrict__ in1, const float* __restrict__ in2,
    short* __restrict__ xb1, short* __restrict__ xb2)
{
    int t = blockIdx.x * 256 + threadIdx.x;          // 2 * NPIX*32/8 threads
    const int N8 = NPIX * 32 / 8;
    const float* src = (t < N8) ? in1 : in2;
    short* dst = (t < N8) ? xb1 : xb2;
    int i = (t < N8) ? t : t - N8;
    float4 a = ld4(src + (size_t)i * 8);
    float4 b = ld4(src + (size_t)i * 8 + 4);
    bf16x8 r;
    r[0] = f2bf(a.x); r[1] = f2bf(a.y); r[2] = f2bf(a.z); r[3] = f2bf(a.w);
    r[4] = f2bf(b.x); r[5] = f2bf(b.y); r[6] = f2bf(b.z); r[7] = f2bf(b.w);
    *(bf16x8*)(dst + (size_t)i * 8) = r;
}

// ---------------------------------------------------------------------------
// Pack conv weights into MFMA B-fragment order (bf16).
// Fragment lane layout (16x16x32): col = lane&15, k = 8*(lane>>4)+j.
// Per direction, 5248 lane-fragments:
//   [0,2304)    wb0: idx = ((t*2+c)*2+n)*64+l   (3x3, ci=64=c*32.., co=32=n*16..)
//   [2304,4608) wb1: idx = (t*4+n)*64+l         (3x3, ci=32, co=64)
//   [4608,5120) wb2: idx = (c*4+n)*64+l         (1x1, ci=64, co=64)
//   [5120,5248) wb3: idx = c*64+l               (1x1, ci=64, co=16)
// ---------------------------------------------------------------------------
__global__ __launch_bounds__(256) void prep_weights_kernel(
    const float* __restrict__ w0a, const float* __restrict__ w1a,
    const float* __restrict__ w2a, const float* __restrict__ w3a,
    const float* __restrict__ w0b, const float* __restrict__ w1b,
    const float* __restrict__ w2b, const float* __restrict__ w3b,
    short* __restrict__ wt0, short* __restrict__ wt1)
{
    int t = blockIdx.x * 256 + threadIdx.x;
    if (t >= 2 * 5248) return;
    int dir = t / 5248;
    int r = t % 5248;
    const float* w0 = dir ? w0b : w0a;
    const float* w1 = dir ? w1b : w1a;
    const float* w2 = dir ? w2b : w2a;
    const float* w3 = dir ? w3b : w3a;
    short* wt = dir ? wt1 : wt0;
    bf16x8 v;
    if (r < 2304) {
        int l = r & 63, n = (r >> 6) & 1, c = (r >> 7) & 1, tp = r >> 8;
#pragma unroll
        for (int j = 0; j < 8; ++j) {
            int ci = c * 32 + 8 * (l >> 4) + j;
            int co = n * 16 + (l & 15);
            v[j] = f2bf(w0[(size_t)(tp * 64 + ci) * 32 + co]);
        }
    } else if (r < 4608) {
        int q = r - 2304;
        int l = q & 63, n = (q >> 6) & 3, tp = q >> 8;
#pragma unroll
        for (int j = 0; j < 8; ++j) {
            int ci = 8 * (l >> 4) + j;
            int co = n * 16 + (l & 15);
            v[j] = f2bf(w1[(size_t)(tp * 32 + ci) * 64 + co]);
        }
    } else if (r < 5120) {
        int q = r - 4608;
        int l = q & 63, n = (q >> 6) & 3, c = q >> 8;
#pragma unroll
        for (int j = 0; j < 8; ++j) {
            int k = 32 * c + 8 * (l >> 4) + j;
            int co = n * 16 + (l & 15);
            v[j] = f2bf(w2[(size_t)k * 64 + co]);
        }
    } else {
        int q = r - 5120;
        int l = q & 63, c = q >> 6;
#pragma unroll
        for (int j = 0; j < 8; ++j) {
            int k = 32 * c + 8 * (l >> 4) + j;
            v[j] = f2bf(w3[(size_t)k * 16 + (l & 15)]);
        }
    }
    *(bf16x8*)(wt + (size_t)r * 8) = v;
}

// ---------------------------------------------------------------------------
// dense_image_warp (TFA semantics) -> bf16 out (feeds conv0).
// ---------------------------------------------------------------------------
__global__ __launch_bounds__(256) void warp_bf16_kernel(
    const float* __restrict__ img, const float* __restrict__ flow,
    short* __restrict__ out)
{
    int gid = blockIdx.x * 256 + threadIdx.x;
    int p   = gid >> 3;
    int c4  = (gid & 7) << 2;
    int b   = p >> 16;
    int i   = (p >> 8) & 255;
    int j   = p & 255;
    float2 f = *(const float2*)(flow + (size_t)p * 2);
    float qy = (float)i - f.x;
    float qx = (float)j - f.y;
    float fyf = fminf(fmaxf(floorf(qy), 0.0f), (float)(H_ - 2));
    float fxf = fminf(fmaxf(floorf(qx), 0.0f), (float)(W_ - 2));
    float ay = fminf(fmaxf(qy - fyf, 0.0f), 1.0f);
    float ax = fminf(fmaxf(qx - fxf, 0.0f), 1.0f);
    int fy = (int)fyf, fx = (int)fxf;
    const float* base = img + ((((size_t)b * H_ + fy) * W_ + fx) << 5) + c4;
    float4 tl = ld4(base);
    float4 tr = ld4(base + 32);
    float4 bl = ld4(base + W_ * 32);
    float4 br = ld4(base + W_ * 32 + 32);
    short4 r;
    { float t = tl.x + ax * (tr.x - tl.x); float u = bl.x + ax * (br.x - bl.x); r.x = f2bf(t + ay * (u - t)); }
    { float t = tl.y + ax * (tr.y - tl.y); float u = bl.y + ax * (br.y - bl.y); r.y = f2bf(t + ay * (u - t)); }
    { float t = tl.z + ax * (tr.z - tl.z); float u = bl.z + ax * (br.z - bl.z); r.z = f2bf(t + ay * (u - t)); }
    { float t = tl.w + ax * (tr.w - tl.w); float u = bl.w + ax * (br.w - bl.w); r.w = f2bf(t + ay * (u - t)); }
    *(short4*)(out + ((size_t)p << 5) + c4) = r;
}

// f32-out variant (final warp, writes d_out; reads original f32 image)
__global__ __launch_bounds__(256) void warp_f32_kernel(
    const float* __restrict__ img, const float* __restrict__ flow,
    float* __restrict__ out)
{
    int gid = blockIdx.x * 256 + threadIdx.x;
    int p   = gid >> 3;
    int c4  = (gid & 7) << 2;
    int b   = p >> 16;
    int i   = (p >> 8) & 255;
    int j   = p & 255;
    float2 f = *(const float2*)(flow + (size_t)p * 2);
    float qy = (float)i - f.x;
    float qx = (float)j - f.y;
    float fyf = fminf(fmaxf(floorf(qy), 0.0f), (float)(H_ - 2));
    float fxf = fminf(fmaxf(floorf(qx), 0.0f), (float)(W_ - 2));
    float ay = fminf(fmaxf(qy - fyf, 0.0f), 1.0f);
    float ax = fminf(fmaxf(qx - fxf, 0.0f), 1.0f);
    int fy = (int)fyf, fx = (int)fxf;
    const float* base = img + ((((size_t)b * H_ + fy) * W_ + fx) << 5) + c4;
    float4 tl = ld4(base);
    float4 tr = ld4(base + 32);
    float4 bl = ld4(base + W_ * 32);
    float4 br = ld4(base + W_ * 32 + 32);
    float4 r;
    { float t = tl.x + ax * (tr.x - tl.x); float u = bl.x + ax * (br.x - bl.x); r.x = t + ay * (u - t); }
    { float t = tl.y + ax * (tr.y - tl.y); float u = bl.y + ax * (br.y - bl.y); r.y = t + ay * (u - t); }
    { float t = tl.z + ax * (tr.z - tl.z); float u = bl.z + ax * (br.z - bl.z); r.z = t + ay * (u - t); }
    { float t = tl.w + ax * (tr.w - tl.w); float u = bl.w + ax * (br.w - bl.w); r.w = t + ay * (u - t); }
    *(float4*)(out + ((size_t)p << 5) + c4) = r;
}

// ---------------------------------------------------------------------------
// conv0 MFMA: 3x3, Cin=64 (chunk0 = xA(other), chunk1 = xB(warped)), Cout=32,
// ReLU -> bf16 h0. 512 thr = 8 waves, 16 px/wave (128 px/block, one image row).
// Per tap: 2 K-chunks x 2 N-subtiles = 4 MFMAs.
// ---------------------------------------------------------------------------
__global__ __launch_bounds__(512) void conv0_mfma_kernel(
    const short* __restrict__ xA, const short* __restrict__ xB,
    const short* __restrict__ wtab, const float* __restrict__ bias,
    short* __restrict__ h0)
{
    __shared__ short swt[2304 * 8];          // 36 KB
    int tid = threadIdx.x;
    for (int i = tid; i < 2304; i += 512)
        ((bf16x8*)swt)[i] = ((const bf16x8*)wtab)[i];
    __syncthreads();

    int wave = tid >> 6, lane = tid & 63;
    int l15 = lane & 15, g = lane >> 4;
    int pbase = blockIdx.x * 128 + wave * 16;
    int px = pbase + l15;
    int y  = (px >> 8) & 255;
    int xl = px & 255;

    const short* ap = xA + ((size_t)px << 5) + g * 8;
    const short* bp = xB + ((size_t)px << 5) + g * 8;
    const bf16x8* wfrag = (const bf16x8*)swt;

    float bv0 = bias[l15], bv1 = bias[16 + l15];
    f32x4 acc0 = {bv0, bv0, bv0, bv0};
    f32x4 acc1 = {bv1, bv1, bv1, bv1};
    const bf16x8 z8 = {0, 0, 0, 0, 0, 0, 0, 0};

#pragma unroll
    for (int dy = -1; dy <= 1; ++dy) {
        if ((unsigned)(y + dy) >= (unsigned)H_) continue;   // uniform per block
#pragma unroll
        for (int dx = -1; dx <= 1; ++dx) {
            bool v = (unsigned)(xl + dx) < (unsigned)W_;
            int off = (dy * W_ + (v ? dx : 0)) << 5;        // shorts (clamped addr)
            bf16x8 a0 = *(const bf16x8*)(ap + off);
            bf16x8 a1 = *(const bf16x8*)(bp + off);
            a0 = v ? a0 : z8;
            a1 = v ? a1 : z8;
            int t = (dy + 1) * 3 + (dx + 1);
            acc0 = __builtin_amdgcn_mfma_f32_16x16x32_bf16(a0, wfrag[(t * 4 + 0) * 64 + lane], acc0, 0, 0, 0);
            acc1 = __builtin_amdgcn_mfma_f32_16x16x32_bf16(a0, wfrag[(t * 4 + 1) * 64 + lane], acc1, 0, 0, 0);
            acc0 = __builtin_amdgcn_mfma_f32_16x16x32_bf16(a1, wfrag[(t * 4 + 2) * 64 + lane], acc0, 0, 0, 0);
            acc1 = __builtin_amdgcn_mfma_f32_16x16x32_bf16(a1, wfrag[(t * 4 + 3) * 64 + lane], acc1, 0, 0, 0);
        }
    }

    // C/D layout: col = l15, row = g*4 + reg
#pragma unroll
    for (int r = 0; r < 4; ++r) {
        size_t row = (size_t)(pbase + g * 4 + r) << 5;
        h0[row + l15]      = f2bf(fmaxf(acc0[r], 0.f));
        h0[row + 16 + l15] = f2bf(fmaxf(acc1[r], 0.f));
    }
}

// ---------------------------------------------------------------------------
// conv1 MFMA fused: 3x3 32->64 relu, 1x1 64->64 relu, 1x1 64->16 relu,
// 1x1 16->2 linear (+flow). 512 thr = 8 waves, 16 px/wave.
// Intermediate activations bounce through wave-private XOR-swizzled LDS tiles
// ([16 px][64 ch] bf16; swz: byte ^= (row&7)<<4 kills the 16-way conflict).
// ---------------------------------------------------------------------------
__global__ __launch_bounds__(512) void conv1_mfma_kernel(
    const short* __restrict__ h0, const short* __restrict__ wtab,
    const float* __restrict__ b1, const float* __restrict__ b2,
    const float* __restrict__ b3, const float* __restrict__ w4,
    const float* __restrict__ b4, const float* __restrict__ flow,
    float* __restrict__ fc)
{
    __shared__ short swt[2944 * 8];                    // wb1|wb2|wb3 = 46 KB
    __shared__ __align__(16) short sx[8][1024];        // 8 waves x [16][64] bf16 = 16 KB
    int tid = threadIdx.x;
    for (int i = tid; i < 2944; i += 512)
        ((bf16x8*)swt)[i] = ((const bf16x8*)wtab)[i];
    __syncthreads();

    int wave = tid >> 6, lane = tid & 63;
    int l15 = lane & 15, g = lane >> 4;
    int pbase = blockIdx.x * 128 + wave * 16;
    int px = pbase + l15;
    int y  = (px >> 8) & 255;
    int xl = px & 255;

    const short* ap = h0 + ((size_t)px << 5) + g * 8;
    const bf16x8* W1 = (const bf16x8*)swt;             // (t*4+n)*64+lane
    const bf16x8* W2 = (const bf16x8*)swt + 2304;      // (c*4+n)*64+lane
    const bf16x8* W3 = (const bf16x8*)swt + 2816;      // c*64+lane
    char* xb = (char*)&sx[wave][0];
    const bf16x8 z8 = {0, 0, 0, 0, 0, 0, 0, 0};

    // ---- GEMM1: 3x3, 32 -> 64 ----
    f32x4 acc[4];
#pragma unroll
    for (int n = 0; n < 4; ++n) {
        float b = b1[n * 16 + l15];
        acc[n] = (f32x4){b, b, b, b};
    }
#pragma unroll
    for (int dy = -1; dy <= 1; ++dy) {
        if ((unsigned)(y + dy) >= (unsigned)H_) continue;
#pragma unroll
        for (int dx = -1; dx <= 1; ++dx) {
            bool v = (unsigned)(xl + dx) < (unsigned)W_;
            int off = (dy * W_ + (v ? dx : 0)) << 5;
            bf16x8 a = *(const bf16x8*)(ap + off);
            a = v ? a : z8;
            int t = (dy + 1) * 3 + (dx + 1);
#pragma unroll
            for (int n = 0; n < 4; ++n)
                acc[n] = __builtin_amdgcn_mfma_f32_16x16x32_bf16(a, W1[(t * 4 + n) * 64 + lane], acc[n], 0, 0, 0);
        }
    }
    // relu -> bf16 -> swizzled LDS [row=px(16)][ch=64]
#pragma unroll
    for (int n = 0; n < 4; ++n)
#pragma unroll
        for (int r = 0; r < 4; ++r) {
            int row = g * 4 + r, ch = n * 16 + l15;
            int byte = (row * 128 + ch * 2) ^ ((row & 7) << 4);
            *(short*)(xb + byte) = f2bf(fmaxf(acc[n][r], 0.f));
        }

    // ---- GEMM2: 1x1, 64 -> 64 ----
#pragma unroll
    for (int n = 0; n < 4; ++n) {
        float b = b2[n * 16 + l15];
        acc[n] = (f32x4){b, b, b, b};
    }
#pragma unroll
    for (int c = 0; c < 2; ++c) {
        int byte = (l15 * 128 + (32 * c + 8 * g) * 2) ^ ((l15 & 7) << 4);
        bf16x8 a = *(const bf16x8*)(xb + byte);
#pragma unroll
        for (int n = 0; n < 4; ++n)
            acc[n] = __builtin_amdgcn_mfma_f32_16x16x32_bf16(a, W2[(c * 4 + n) * 64 + lane], acc[n], 0, 0, 0);
    }
#pragma unroll
    for (int n = 0; n < 4; ++n)
#pragma unroll
        for (int r = 0; r < 4; ++r) {
            int row = g * 4 + r, ch = n * 16 + l15;
            int byte = (row * 128 + ch * 2) ^ ((row & 7) << 4);
            *(short*)(xb + byte) = f2bf(fmaxf(acc[n][r], 0.f));
        }

    // ---- GEMM3: 1x1, 64 -> 16 ----
    float b3v = b3[l15];
    f32x4 acc3 = {b3v, b3v, b3v, b3v};
#pragma unroll
    for (int c = 0; c < 2; ++c) {
        int byte = (l15 * 128 + (32 * c + 8 * g) * 2) ^ ((l15 & 7) << 4);
        bf16x8 a = *(const bf16x8*)(xb + byte);
        acc3 = __builtin_amdgcn_mfma_f32_16x16x32_bf16(a, W3[c * 64 + lane], acc3, 0, 0, 0);
    }

    // ---- 1x1, 16 -> 2 (f32) + flow add; 16-lane xor reduction over ch ----
    float w40 = w4[l15 * 2 + 0], w41 = w4[l15 * 2 + 1];
    float bb0 = b4[0], bb1 = b4[1];
#pragma unroll
    for (int r = 0; r < 4; ++r) {
        float v = fmaxf(acc3[r], 0.f);
        float s0 = v * w40, s1 = v * w41;
#pragma unroll
        for (int m = 1; m < 16; m <<= 1) {
            s0 += __shfl_xor(s0, m);
            s1 += __shfl_xor(s1, m);
        }
        if (l15 == 0) {
            int pr = pbase + g * 4 + r;
            float2 fl = *(const float2*)(flow + (size_t)pr * 2);
            float2 o; o.x = fl.x + bb0 + s0; o.y = fl.y + bb1 + s1;
            *(float2*)(fc + (size_t)pr * 2) = o;
        }
    }
}

// ---------------------------------------------------------------------------
// 2x bilinear upsample (jax half-pixel), unchanged from round 5.
// ---------------------------------------------------------------------------
__global__ __launch_bounds__(256) void upsample_kernel(
    const float* __restrict__ fc, float* __restrict__ out)
{
    int gid = blockIdx.x * 256 + threadIdx.x;
    int b  = gid >> 18;
    int oy = (gid >> 9) & 511;
    int ox = gid & 511;
    float iy = 0.5f * (float)oy - 0.25f;
    float ix = 0.5f * (float)ox - 0.25f;
    float y0f = floorf(iy), x0f = floorf(ix);
    float wy = iy - y0f, wx = ix - x0f;
    int y0 = min(max((int)y0f, 0), H_ - 1);
    int y1 = min(max((int)y0f + 1, 0), H_ - 1);
    int x0 = min(max((int)x0f, 0), W_ - 1);
    int x1 = min(max((int)x0f + 1, 0), W_ - 1);
    float2 v00 = *(const float2*)(fc + (((size_t)b * H_ + y0) * W_ + x0) * 2);
    float2 v01 = *(const float2*)(fc + (((size_t)b * H_ + y0) * W_ + x1) * 2);
    float2 v10 = *(const float2*)(fc + (((size_t)b * H_ + y1) * W_ + x0) * 2);
    float2 v11 = *(const float2*)(fc + (((size_t)b * H_ + y1) * W_ + x1) * 2);
    float2 r;
    { float t = v00.x + wx * (v01.x - v00.x); float u = v10.x + wx * (v11.x - v10.x); r.x = t + wy * (u - t); }
    { float t = v00.y + wx * (v01.y - v00.y); float u = v10.y + wx * (v11.y - v10.y); r.y = t + wy * (u - t); }
    *(float2*)(out + (size_t)gid * 2) = r;
}

// ---------------------------------------------------------------------------
// d_in order = setup_inputs() dict order (interleaved per layer):
//   w_i = d_in[4+4i+2d], b_i = d_in[5+4i+2d]
// ---------------------------------------------------------------------------
extern "C" void kernel_launch(void* const* d_in, const int* in_sizes, int n_in,
                              void* d_out, int out_size, void* d_ws, size_t ws_size,
                              hipStream_t stream)
{
    (void)in_sizes; (void)n_in; (void)out_size; (void)ws_size;
    const float* input1 = (const float*)d_in[0];
    const float* input2 = (const float*)d_in[1];
    char* wsb = (char*)d_ws;
    short* xb1  = (short*)(wsb);                       // NPIX*32 bf16 = 32MB
    short* xb2  = (short*)(wsb + 33554432);            // 32MB
    short* wbf  = (short*)(wsb + 67108864);            // warped bf16, 32MB
    short* h0   = (short*)(wsb + 100663296);           // 32MB
    float* fcbuf= (float*)(wsb + 134217728);           // NPIX*2 f32 = 4MB
    short* wt0  = (short*)(wsb + 138412032);           // 5248*8 shorts
    short* wt1  = (short*)(wsb + 138412032 + 5248 * 16);
    float* outf = (float*)d_out;

    cvt_inputs_kernel<<<NPIX * 64 / 8 / 256, 256, 0, stream>>>(input1, input2, xb1, xb2);
    prep_weights_kernel<<<(2 * 5248 + 255) / 256, 256, 0, stream>>>(
        (const float*)d_in[4],  (const float*)d_in[8],  (const float*)d_in[12], (const float*)d_in[16],
        (const float*)d_in[6],  (const float*)d_in[10], (const float*)d_in[14], (const float*)d_in[18],
        wt0, wt1);

    for (int d = 0; d < 2; ++d) {
        const float* src   = (d == 0) ? input1 : input2;
        const short* xoth  = (d == 0) ? xb2 : xb1;
        const float* flow  = (const float*)d_in[2 + d];
        short* wt = (d == 0) ? wt0 : wt1;
        const float* b0 = (const float*)d_in[5 + 2 * d];
        const float* b1 = (const float*)d_in[9 + 2 * d];
        const float* b2 = (const float*)d_in[13 + 2 * d];
        const float* b3 = (const float*)d_in[17 + 2 * d];
        const float* w4 = (const float*)d_in[20 + 2 * d];
        const float* b4 = (const float*)d_in[21 + 2 * d];
        float* out_warp = outf + (size_t)d * NPIX * 32;
        float* out_up   = outf + (size_t)2 * NPIX * 32 + (size_t)d * (B_ * 512 * 512 * 2);

        warp_bf16_kernel<<<NPIX * 8 / 256, 256, 0, stream>>>(src, flow, wbf);
        conv0_mfma_kernel<<<NPIX / 128, 512, 0, stream>>>(xoth, wbf, wt, b0, h0);
        conv1_mfma_kernel<<<NPIX / 128, 512, 0, stream>>>(h0, wt + 2304 * 8, b1, b2, b3, w4, b4, flow, fcbuf);
        warp_f32_kernel<<<NPIX * 8 / 256, 256, 0, stream>>>(src, fcbuf, out_warp);
        upsample_kernel<<<B_ * 512 * 512 / 256, 256, 0, stream>>>(fcbuf, out_up);
    }
}

// Round 11
// 593.177 us; speedup vs baseline: 7.1781x; 1.0386x over previous
//
#include <hip/hip_runtime.h>
#include <hip/hip_bf16.h>
#include <cstddef>

#define B_ 8
#define H_ 256
#define W_ 256

static constexpr int NPIX = B_ * H_ * W_;   // 524288

typedef __attribute__((ext_vector_type(8))) short bf16x8;   // 8 bf16 (4 VGPRs)
typedef __attribute__((ext_vector_type(4))) float f32x4;

__device__ __forceinline__ float4 ld4(const float* p) { return *(const float4*)p; }

// RNE f32 -> bf16 bits (finite data only)
__device__ __forceinline__ short f2bf(float x) {
    unsigned u = __float_as_uint(x);
    unsigned r = (u + 0x7fffu + ((u >> 16) & 1u)) >> 16;
    return (short)r;
}

// ---------------------------------------------------------------------------
// Convert f32 NHWC inputs -> bf16 copies (xb1, xb2). 8 floats/thread.
// ---------------------------------------------------------------------------
__global__ __launch_bounds__(256) void cvt_inputs_kernel(
    const float* __restrict__ in1, const float* __restrict__ in2,
    short* __restrict__ xb1, short* __restrict__ xb2)
{
    int t = blockIdx.x * 256 + threadIdx.x;          // 2 * NPIX*32/8 threads
    const int N8 = NPIX * 32 / 8;
    const float* src = (t < N8) ? in1 : in2;
    short* dst = (t < N8) ? xb1 : xb2;
    int i = (t < N8) ? t : t - N8;
    float4 a = ld4(src + (size_t)i * 8);
    float4 b = ld4(src + (size_t)i * 8 + 4);
    bf16x8 r;
    r[0] = f2bf(a.x); r[1] = f2bf(a.y); r[2] = f2bf(a.z); r[3] = f2bf(a.w);
    r[4] = f2bf(b.x); r[5] = f2bf(b.y); r[6] = f2bf(b.z); r[7] = f2bf(b.w);
    *(bf16x8*)(dst + (size_t)i * 8) = r;
}

// ---------------------------------------------------------------------------
// Pack conv weights into MFMA B-fragment order (bf16).
// Fragment lane layout (16x16x32): col = lane&15, k = 8*(lane>>4)+j.
// Per direction, 5248 lane-fragments:
//   [0,2304)    wb0: idx = ((t*2+c)*2+n)*64+l   (3x3, ci=64, co=32)
//   [2304,4608) wb1: idx = (t*4+n)*64+l         (3x3, ci=32, co=64)
//   [4608,5120) wb2: idx = (c*4+n)*64+l         (1x1, ci=64, co=64)
//   [5120,5248) wb3: idx = c*64+l               (1x1, ci=64, co=16)
// ---------------------------------------------------------------------------
__global__ __launch_bounds__(256) void prep_weights_kernel(
    const float* __restrict__ w0a, const float* __restrict__ w1a,
    const float* __restrict__ w2a, const float* __restrict__ w3a,
    const float* __restrict__ w0b, const float* __restrict__ w1b,
    const float* __restrict__ w2b, const float* __restrict__ w3b,
    short* __restrict__ wt0, short* __restrict__ wt1)
{
    int t = blockIdx.x * 256 + threadIdx.x;
    if (t >= 2 * 5248) return;
    int dir = t / 5248;
    int r = t % 5248;
    const float* w0 = dir ? w0b : w0a;
    const float* w1 = dir ? w1b : w1a;
    const float* w2 = dir ? w2b : w2a;
    const float* w3 = dir ? w3b : w3a;
    short* wt = dir ? wt1 : wt0;
    bf16x8 v;
    if (r < 2304) {
        int l = r & 63, n = (r >> 6) & 1, c = (r >> 7) & 1, tp = r >> 8;
#pragma unroll
        for (int j = 0; j < 8; ++j) {
            int ci = c * 32 + 8 * (l >> 4) + j;
            int co = n * 16 + (l & 15);
            v[j] = f2bf(w0[(size_t)(tp * 64 + ci) * 32 + co]);
        }
    } else if (r < 4608) {
        int q = r - 2304;
        int l = q & 63, n = (q >> 6) & 3, tp = q >> 8;
#pragma unroll
        for (int j = 0; j < 8; ++j) {
            int ci = 8 * (l >> 4) + j;
            int co = n * 16 + (l & 15);
            v[j] = f2bf(w1[(size_t)(tp * 32 + ci) * 64 + co]);
        }
    } else if (r < 5120) {
        int q = r - 4608;
        int l = q & 63, n = (q >> 6) & 3, c = q >> 8;
#pragma unroll
        for (int j = 0; j < 8; ++j) {
            int k = 32 * c + 8 * (l >> 4) + j;
            int co = n * 16 + (l & 15);
            v[j] = f2bf(w2[(size_t)k * 64 + co]);
        }
    } else {
        int q = r - 5120;
        int l = q & 63, c = q >> 6;
#pragma unroll
        for (int j = 0; j < 8; ++j) {
            int k = 32 * c + 8 * (l >> 4) + j;
            v[j] = f2bf(w3[(size_t)k * 16 + (l & 15)]);
        }
    }
    *(bf16x8*)(wt + (size_t)r * 8) = v;
}

// ---------------------------------------------------------------------------
// dense_image_warp (TFA semantics) -> bf16, both directions in one launch.
// ---------------------------------------------------------------------------
__global__ __launch_bounds__(256) void warp_bf16_kernel(
    const float* __restrict__ in1, const float* __restrict__ in2,
    const float* __restrict__ fl12, const float* __restrict__ fl21,
    short* __restrict__ wbf)
{
    int gid = blockIdx.x * 256 + threadIdx.x;        // 2 * NPIX * 8
    int d   = (gid >= NPIX * 8);
    int g2  = gid - (d ? NPIX * 8 : 0);
    const float* img  = d ? in2 : in1;
    const float* flow = d ? fl21 : fl12;
    short* out = wbf + (size_t)d * NPIX * 32;

    int p   = g2 >> 3;
    int c4  = (g2 & 7) << 2;
    int b   = p >> 16;
    int i   = (p >> 8) & 255;
    int j   = p & 255;
    float2 f = *(const float2*)(flow + (size_t)p * 2);
    float qy = (float)i - f.x;
    float qx = (float)j - f.y;
    float fyf = fminf(fmaxf(floorf(qy), 0.0f), (float)(H_ - 2));
    float fxf = fminf(fmaxf(floorf(qx), 0.0f), (float)(W_ - 2));
    float ay = fminf(fmaxf(qy - fyf, 0.0f), 1.0f);
    float ax = fminf(fmaxf(qx - fxf, 0.0f), 1.0f);
    int fy = (int)fyf, fx = (int)fxf;
    const float* base = img + ((((size_t)b * H_ + fy) * W_ + fx) << 5) + c4;
    float4 tl = ld4(base);
    float4 tr = ld4(base + 32);
    float4 bl = ld4(base + W_ * 32);
    float4 br = ld4(base + W_ * 32 + 32);
    short4 r;
    { float t = tl.x + ax * (tr.x - tl.x); float u = bl.x + ax * (br.x - bl.x); r.x = f2bf(t + ay * (u - t)); }
    { float t = tl.y + ax * (tr.y - tl.y); float u = bl.y + ax * (br.y - bl.y); r.y = f2bf(t + ay * (u - t)); }
    { float t = tl.z + ax * (tr.z - tl.z); float u = bl.z + ax * (br.z - bl.z); r.z = f2bf(t + ay * (u - t)); }
    { float t = tl.w + ax * (tr.w - tl.w); float u = bl.w + ax * (br.w - bl.w); r.w = f2bf(t + ay * (u - t)); }
    *(short4*)(out + ((size_t)p << 5) + c4) = r;
}

// Final warp: f32 out to d_out, both directions (flow = fc per dir).
__global__ __launch_bounds__(256) void warp_f32_kernel(
    const float* __restrict__ in1, const float* __restrict__ in2,
    const float* __restrict__ fcb, float* __restrict__ outf)
{
    int gid = blockIdx.x * 256 + threadIdx.x;        // 2 * NPIX * 8
    int d   = (gid >= NPIX * 8);
    int g2  = gid - (d ? NPIX * 8 : 0);
    const float* img  = d ? in2 : in1;
    const float* flow = fcb + (size_t)d * NPIX * 2;
    float* out = outf + (size_t)d * NPIX * 32;

    int p   = g2 >> 3;
    int c4  = (g2 & 7) << 2;
    int b   = p >> 16;
    int i   = (p >> 8) & 255;
    int j   = p & 255;
    float2 f = *(const float2*)(flow + (size_t)p * 2);
    float qy = (float)i - f.x;
    float qx = (float)j - f.y;
    float fyf = fminf(fmaxf(floorf(qy), 0.0f), (float)(H_ - 2));
    float fxf = fminf(fmaxf(floorf(qx), 0.0f), (float)(W_ - 2));
    float ay = fminf(fmaxf(qy - fyf, 0.0f), 1.0f);
    float ax = fminf(fmaxf(qx - fxf, 0.0f), 1.0f);
    int fy = (int)fyf, fx = (int)fxf;
    const float* base = img + ((((size_t)b * H_ + fy) * W_ + fx) << 5) + c4;
    float4 tl = ld4(base);
    float4 tr = ld4(base + 32);
    float4 bl = ld4(base + W_ * 32);
    float4 br = ld4(base + W_ * 32 + 32);
    float4 r;
    { float t = tl.x + ax * (tr.x - tl.x); float u = bl.x + ax * (br.x - bl.x); r.x = t + ay * (u - t); }
    { float t = tl.y + ax * (tr.y - tl.y); float u = bl.y + ax * (br.y - bl.y); r.y = t + ay * (u - t); }
    { float t = tl.z + ax * (tr.z - tl.z); float u = bl.z + ax * (br.z - bl.z); r.z = t + ay * (u - t); }
    { float t = tl.w + ax * (tr.w - tl.w); float u = bl.w + ax * (br.w - bl.w); r.w = t + ay * (u - t); }
    *(float4*)(out + ((size_t)p << 5) + c4) = r;
}

// ---------------------------------------------------------------------------
// conv0 MFMA, both dirs, 2 M-tiles/wave: 3x3, Cin=64 (A=other img, B=warped),
// Cout=32, ReLU -> bf16 h0. Block = 512 thr = 8 waves = 256 px = one row
// (y uniform). Each weight ds_read feeds 2 MFMAs (2 pixel tiles).
// ---------------------------------------------------------------------------
__global__ __launch_bounds__(512) void conv0_mfma_kernel(
    const short* __restrict__ xb1, const short* __restrict__ xb2,
    const short* __restrict__ wbf,
    const short* __restrict__ wt0, const short* __restrict__ wt1,
    const float* __restrict__ b0a, const float* __restrict__ b0b,
    short* __restrict__ h0)
{
    __shared__ short swt[2304 * 8];          // 36 KB
    int d   = blockIdx.x >> 11;              // 2048 blocks per dir
    int bid = blockIdx.x & 2047;
    const short* xoth = d ? xb1 : xb2;
    const short* xw   = wbf + (size_t)d * NPIX * 32;
    const short* wtab = d ? wt1 : wt0;
    const float* bias = d ? b0b : b0a;
    short* out = h0 + (size_t)d * NPIX * 32;

    int tid = threadIdx.x;
    for (int i = tid; i < 2304; i += 512)
        ((bf16x8*)swt)[i] = ((const bf16x8*)wtab)[i];
    __syncthreads();

    int wave = tid >> 6, lane = tid & 63;
    int l15 = lane & 15, g = lane >> 4;
    int prow = bid * 256;                    // row start pixel
    int y    = bid & 255;
    int t0   = prow + wave * 32;             // tile0 base px
    int xl0  = wave * 32 + l15;              // column of tile0 lane px
    int xl1  = xl0 + 16;

    const short* a0p = xoth + ((size_t)(t0 + l15) << 5) + g * 8;
    const short* a1p = a0p + (16 << 5);
    const short* b0p = xw + ((size_t)(t0 + l15) << 5) + g * 8;
    const short* b1p = b0p + (16 << 5);
    const bf16x8* wfrag = (const bf16x8*)swt;

    float bv0 = bias[l15], bv1 = bias[16 + l15];
    f32x4 acc00 = {bv0, bv0, bv0, bv0};      // tile0, co 0-15
    f32x4 acc01 = {bv1, bv1, bv1, bv1};      // tile0, co 16-31
    f32x4 acc10 = {bv0, bv0, bv0, bv0};      // tile1, co 0-15
    f32x4 acc11 = {bv1, bv1, bv1, bv1};
    const bf16x8 z8 = {0, 0, 0, 0, 0, 0, 0, 0};

#pragma unroll
    for (int dy = -1; dy <= 1; ++dy) {
        if ((unsigned)(y + dy) >= (unsigned)H_) continue;   // uniform per block
#pragma unroll
        for (int dx = -1; dx <= 1; ++dx) {
            bool v0 = (unsigned)(xl0 + dx) < (unsigned)W_;
            bool v1 = (unsigned)(xl1 + dx) < (unsigned)W_;
            int off0 = (dy * W_ + (v0 ? dx : 0)) << 5;
            int off1 = (dy * W_ + (v1 ? dx : 0)) << 5;
            bf16x8 aA0 = *(const bf16x8*)(a0p + off0);
            bf16x8 aB0 = *(const bf16x8*)(b0p + off0);
            bf16x8 aA1 = *(const bf16x8*)(a1p + off1);
            bf16x8 aB1 = *(const bf16x8*)(b1p + off1);
            aA0 = v0 ? aA0 : z8;  aB0 = v0 ? aB0 : z8;
            aA1 = v1 ? aA1 : z8;  aB1 = v1 ? aB1 : z8;
            int t = (dy + 1) * 3 + (dx + 1);
            bf16x8 w0 = wfrag[(t * 4 + 0) * 64 + lane];
            bf16x8 w1 = wfrag[(t * 4 + 1) * 64 + lane];
            bf16x8 w2 = wfrag[(t * 4 + 2) * 64 + lane];
            bf16x8 w3 = wfrag[(t * 4 + 3) * 64 + lane];
            acc00 = __builtin_amdgcn_mfma_f32_16x16x32_bf16(aA0, w0, acc00, 0, 0, 0);
            acc01 = __builtin_amdgcn_mfma_f32_16x16x32_bf16(aA0, w1, acc01, 0, 0, 0);
            acc10 = __builtin_amdgcn_mfma_f32_16x16x32_bf16(aA1, w0, acc10, 0, 0, 0);
            acc11 = __builtin_amdgcn_mfma_f32_16x16x32_bf16(aA1, w1, acc11, 0, 0, 0);
            acc00 = __builtin_amdgcn_mfma_f32_16x16x32_bf16(aB0, w2, acc00, 0, 0, 0);
            acc01 = __builtin_amdgcn_mfma_f32_16x16x32_bf16(aB0, w3, acc01, 0, 0, 0);
            acc10 = __builtin_amdgcn_mfma_f32_16x16x32_bf16(aB1, w2, acc10, 0, 0, 0);
            acc11 = __builtin_amdgcn_mfma_f32_16x16x32_bf16(aB1, w3, acc11, 0, 0, 0);
        }
    }

    // C/D: col(co)=l15, row(px)=g*4+r
#pragma unroll
    for (int r = 0; r < 4; ++r) {
        size_t r0 = (size_t)(t0 + g * 4 + r) << 5;
        size_t r1 = (size_t)(t0 + 16 + g * 4 + r) << 5;
        out[r0 + l15]      = f2bf(fmaxf(acc00[r], 0.f));
        out[r0 + 16 + l15] = f2bf(fmaxf(acc01[r], 0.f));
        out[r1 + l15]      = f2bf(fmaxf(acc10[r], 0.f));
        out[r1 + 16 + l15] = f2bf(fmaxf(acc11[r], 0.f));
    }
}

// ---------------------------------------------------------------------------
// conv1 MFMA fused, both dirs, 2 M-tiles/wave: 3x3 32->64 relu, 1x1 64->64
// relu, 1x1 64->16 relu, 1x1 16->2 linear (+flow). Wave-private swizzled LDS
// tile [32 px][64 ch] bf16 between GEMMs (byte ^= (row&7)<<4).
// ---------------------------------------------------------------------------
__global__ __launch_bounds__(512) void conv1_mfma_kernel(
    const short* __restrict__ h0,
    const short* __restrict__ wt0, const short* __restrict__ wt1,
    const float* __restrict__ b1a, const float* __restrict__ b1b,
    const float* __restrict__ b2a, const float* __restrict__ b2b,
    const float* __restrict__ b3a, const float* __restrict__ b3b,
    const float* __restrict__ w4a, const float* __restrict__ w4b,
    const float* __restrict__ b4a, const float* __restrict__ b4b,
    const float* __restrict__ fl12, const float* __restrict__ fl21,
    float* __restrict__ fcb)
{
    __shared__ short swt[2944 * 8];                 // wb1|wb2|wb3 = 46 KB
    __shared__ __align__(16) short sx[8][2048];     // 8 waves x [32][64] = 32 KB
    int d   = blockIdx.x >> 11;
    int bid = blockIdx.x & 2047;
    const short* hsrc = h0 + (size_t)d * NPIX * 32;
    const short* wtab = (d ? wt1 : wt0) + 2304 * 8;
    const float* b1 = d ? b1b : b1a;
    const float* b2 = d ? b2b : b2a;
    const float* b3 = d ? b3b : b3a;
    const float* w4 = d ? w4b : w4a;
    const float* b4 = d ? b4b : b4a;
    const float* flow = d ? fl21 : fl12;
    float* fc = fcb + (size_t)d * NPIX * 2;

    int tid = threadIdx.x;
    for (int i = tid; i < 2944; i += 512)
        ((bf16x8*)swt)[i] = ((const bf16x8*)wtab)[i];
    __syncthreads();

    int wave = tid >> 6, lane = tid & 63;
    int l15 = lane & 15, g = lane >> 4;
    int prow = bid * 256;
    int y    = bid & 255;
    int t0   = prow + wave * 32;
    int xl0  = wave * 32 + l15;
    int xl1  = xl0 + 16;

    const short* a0p = hsrc + ((size_t)(t0 + l15) << 5) + g * 8;
    const short* a1p = a0p + (16 << 5);
    const bf16x8* W1 = (const bf16x8*)swt;          // (t*4+n)*64+lane
    const bf16x8* W2 = (const bf16x8*)swt + 2304;   // (c*4+n)*64+lane
    const bf16x8* W3 = (const bf16x8*)swt + 2816;   // c*64+lane
    char* xb = (char*)&sx[wave][0];
    const bf16x8 z8 = {0, 0, 0, 0, 0, 0, 0, 0};

    // ---- GEMM1: 3x3, 32 -> 64 ----
    f32x4 acc0[4], acc1[4];
#pragma unroll
    for (int n = 0; n < 4; ++n) {
        float b = b1[n * 16 + l15];
        acc0[n] = (f32x4){b, b, b, b};
        acc1[n] = (f32x4){b, b, b, b};
    }
#pragma unroll
    for (int dy = -1; dy <= 1; ++dy) {
        if ((unsigned)(y + dy) >= (unsigned)H_) continue;
#pragma unroll
        for (int dx = -1; dx <= 1; ++dx) {
            bool v0 = (unsigned)(xl0 + dx) < (unsigned)W_;
            bool v1 = (unsigned)(xl1 + dx) < (unsigned)W_;
            int off0 = (dy * W_ + (v0 ? dx : 0)) << 5;
            int off1 = (dy * W_ + (v1 ? dx : 0)) << 5;
            bf16x8 a0 = *(const bf16x8*)(a0p + off0);
            bf16x8 a1 = *(const bf16x8*)(a1p + off1);
            a0 = v0 ? a0 : z8;
            a1 = v1 ? a1 : z8;
            int t = (dy + 1) * 3 + (dx + 1);
#pragma unroll
            for (int n = 0; n < 4; ++n) {
                bf16x8 w = W1[(t * 4 + n) * 64 + lane];
                acc0[n] = __builtin_amdgcn_mfma_f32_16x16x32_bf16(a0, w, acc0[n], 0, 0, 0);
                acc1[n] = __builtin_amdgcn_mfma_f32_16x16x32_bf16(a1, w, acc1[n], 0, 0, 0);
            }
        }
    }
    // relu -> bf16 -> swizzled LDS rows 0..31
#pragma unroll
    for (int n = 0; n < 4; ++n)
#pragma unroll
        for (int r = 0; r < 4; ++r) {
            int row0 = g * 4 + r, ch = n * 16 + l15;
            int by0 = (row0 * 128 + ch * 2) ^ ((row0 & 7) << 4);
            int by1 = ((row0 + 16) * 128 + ch * 2) ^ ((row0 & 7) << 4);
            *(short*)(xb + by0) = f2bf(fmaxf(acc0[n][r], 0.f));
            *(short*)(xb + by1) = f2bf(fmaxf(acc1[n][r], 0.f));
        }

    // ---- GEMM2: 1x1, 64 -> 64 ----
#pragma unroll
    for (int n = 0; n < 4; ++n) {
        float b = b2[n * 16 + l15];
        acc0[n] = (f32x4){b, b, b, b};
        acc1[n] = (f32x4){b, b, b, b};
    }
#pragma unroll
    for (int c = 0; c < 2; ++c) {
        int by0 = (l15 * 128 + (32 * c + 8 * g) * 2) ^ ((l15 & 7) << 4);
        int by1 = ((l15 + 16) * 128 + (32 * c + 8 * g) * 2) ^ ((l15 & 7) << 4);
        bf16x8 a0 = *(const bf16x8*)(xb + by0);
        bf16x8 a1 = *(const bf16x8*)(xb + by1);
#pragma unroll
        for (int n = 0; n < 4; ++n) {
            bf16x8 w = W2[(c * 4 + n) * 64 + lane];
            acc0[n] = __builtin_amdgcn_mfma_f32_16x16x32_bf16(a0, w, acc0[n], 0, 0, 0);
            acc1[n] = __builtin_amdgcn_mfma_f32_16x16x32_bf16(a1, w, acc1[n], 0, 0, 0);
        }
    }
#pragma unroll
    for (int n = 0; n < 4; ++n)
#pragma unroll
        for (int r = 0; r < 4; ++r) {
            int row0 = g * 4 + r, ch = n * 16 + l15;
            int by0 = (row0 * 128 + ch * 2) ^ ((row0 & 7) << 4);
            int by1 = ((row0 + 16) * 128 + ch * 2) ^ ((row0 & 7) << 4);
            *(short*)(xb + by0) = f2bf(fmaxf(acc0[n][r], 0.f));
            *(short*)(xb + by1) = f2bf(fmaxf(acc1[n][r], 0.f));
        }

    // ---- GEMM3: 1x1, 64 -> 16 ----
    float b3v = b3[l15];
    f32x4 acc3a = {b3v, b3v, b3v, b3v};
    f32x4 acc3b = {b3v, b3v, b3v, b3v};
#pragma unroll
    for (int c = 0; c < 2; ++c) {
        int by0 = (l15 * 128 + (32 * c + 8 * g) * 2) ^ ((l15 & 7) << 4);
        int by1 = ((l15 + 16) * 128 + (32 * c + 8 * g) * 2) ^ ((l15 & 7) << 4);
        bf16x8 a0 = *(const bf16x8*)(xb + by0);
        bf16x8 a1 = *(const bf16x8*)(xb + by1);
        bf16x8 w = W3[c * 64 + lane];
        acc3a = __builtin_amdgcn_mfma_f32_16x16x32_bf16(a0, w, acc3a, 0, 0, 0);
        acc3b = __builtin_amdgcn_mfma_f32_16x16x32_bf16(a1, w, acc3b, 0, 0, 0);
    }

    // ---- 1x1, 16 -> 2 (f32) + flow add; 16-lane xor reduction over ch ----
    float w40 = w4[l15 * 2 + 0], w41 = w4[l15 * 2 + 1];
    float bb0 = b4[0], bb1 = b4[1];
#pragma unroll
    for (int tt = 0; tt < 2; ++tt) {
        f32x4 a3 = tt ? acc3b : acc3a;
#pragma unroll
        for (int r = 0; r < 4; ++r) {
            float v = fmaxf(a3[r], 0.f);
            float s0 = v * w40, s1 = v * w41;
#pragma unroll
            for (int m = 1; m < 16; m <<= 1) {
                s0 += __shfl_xor(s0, m);
                s1 += __shfl_xor(s1, m);
            }
            if (l15 == 0) {
                int pr = t0 + tt * 16 + g * 4 + r;
                float2 fl = *(const float2*)(flow + (size_t)pr * 2);
                float2 o; o.x = fl.x + bb0 + s0; o.y = fl.y + bb1 + s1;
                *(float2*)(fc + (size_t)pr * 2) = o;
            }
        }
    }
}

// ---------------------------------------------------------------------------
// 2x bilinear upsample (jax half-pixel), both dirs.
// ---------------------------------------------------------------------------
__global__ __launch_bounds__(256) void upsample_kernel(
    const float* __restrict__ fcb, float* __restrict__ outup)
{
    int gid = blockIdx.x * 256 + threadIdx.x;       // 2 * B*512*512
    const int NUP = B_ * 512 * 512;
    int d  = (gid >= NUP);
    int g2 = gid - (d ? NUP : 0);
    const float* fc = fcb + (size_t)d * NPIX * 2;
    float* out = outup + (size_t)d * NUP * 2;

    int b  = g2 >> 18;
    int oy = (g2 >> 9) & 511;
    int ox = g2 & 511;
    float iy = 0.5f * (float)oy - 0.25f;
    float ix = 0.5f * (float)ox - 0.25f;
    float y0f = floorf(iy), x0f = floorf(ix);
    float wy = iy - y0f, wx = ix - x0f;
    int y0 = min(max((int)y0f, 0), H_ - 1);
    int y1 = min(max((int)y0f + 1, 0), H_ - 1);
    int x0 = min(max((int)x0f, 0), W_ - 1);
    int x1 = min(max((int)x0f + 1, 0), W_ - 1);
    float2 v00 = *(const float2*)(fc + (((size_t)b * H_ + y0) * W_ + x0) * 2);
    float2 v01 = *(const float2*)(fc + (((size_t)b * H_ + y0) * W_ + x1) * 2);
    float2 v10 = *(const float2*)(fc + (((size_t)b * H_ + y1) * W_ + x0) * 2);
    float2 v11 = *(const float2*)(fc + (((size_t)b * H_ + y1) * W_ + x1) * 2);
    float2 r;
    { float t = v00.x + wx * (v01.x - v00.x); float u = v10.x + wx * (v11.x - v10.x); r.x = t + wy * (u - t); }
    { float t = v00.y + wx * (v01.y - v00.y); float u = v10.y + wx * (v11.y - v10.y); r.y = t + wy * (u - t); }
    *(float2*)(out + (size_t)g2 * 2) = r;
}

// ---------------------------------------------------------------------------
// d_in order = setup_inputs() dict order (interleaved per layer):
//   w_i = d_in[4+4i+2d], b_i = d_in[5+4i+2d]
// ---------------------------------------------------------------------------
extern "C" void kernel_launch(void* const* d_in, const int* in_sizes, int n_in,
                              void* d_out, int out_size, void* d_ws, size_t ws_size,
                              hipStream_t stream)
{
    (void)in_sizes; (void)n_in; (void)out_size; (void)ws_size;
    const float* input1 = (const float*)d_in[0];
    const float* input2 = (const float*)d_in[1];
    const float* fl12 = (const float*)d_in[2];
    const float* fl21 = (const float*)d_in[3];
    char* wsb = (char*)d_ws;
    short* xb1  = (short*)(wsb);                       // 32MB
    short* xb2  = (short*)(wsb + 33554432);            // 32MB
    short* wbf  = (short*)(wsb + 67108864);            // 2 x 32MB
    short* h0   = (short*)(wsb + 134217728);           // 2 x 32MB
    float* fcb  = (float*)(wsb + 201326592);           // 2 x 4MB
    short* wt0  = (short*)(wsb + 209715200);           // 5248*16 B
    short* wt1  = (short*)(wsb + 209715200 + 5248 * 16);
    float* outf = (float*)d_out;
    float* outup = outf + (size_t)2 * NPIX * 32;

    cvt_inputs_kernel<<<NPIX * 64 / 8 / 256, 256, 0, stream>>>(input1, input2, xb1, xb2);
    prep_weights_kernel<<<(2 * 5248 + 255) / 256, 256, 0, stream>>>(
        (const float*)d_in[4],  (const float*)d_in[8],  (const float*)d_in[12], (const float*)d_in[16],
        (const float*)d_in[6],  (const float*)d_in[10], (const float*)d_in[14], (const float*)d_in[18],
        wt0, wt1);
    warp_bf16_kernel<<<2 * NPIX * 8 / 256, 256, 0, stream>>>(input1, input2, fl12, fl21, wbf);
    conv0_mfma_kernel<<<2 * NPIX / 256, 512, 0, stream>>>(
        xb1, xb2, wbf, wt0, wt1,
        (const float*)d_in[5], (const float*)d_in[7], h0);
    conv1_mfma_kernel<<<2 * NPIX / 256, 512, 0, stream>>>(
        h0, wt0, wt1,
        (const float*)d_in[9],  (const float*)d_in[11],
        (const float*)d_in[13], (const float*)d_in[15],
        (const float*)d_in[17], (const float*)d_in[19],
        (const float*)d_in[20], (const float*)d_in[22],
        (const float*)d_in[21], (const float*)d_in[23],
        fl12, fl21, fcb);
    warp_f32_kernel<<<2 * NPIX * 8 / 256, 256, 0, stream>>>(input1, input2, fcb, outf);
    upsample_kernel<<<2 * B_ * 512 * 512 / 256, 256, 0, stream>>>(fcb, outup);
}